// Round 8
// baseline (153.570 us; speedup 1.0000x reference)
//
#include <hip/hip_runtime.h>
#include <hip/hip_bf16.h>

#define NN 4096

typedef unsigned short u16;
typedef __attribute__((ext_vector_type(8))) short short8;
typedef __attribute__((ext_vector_type(4))) float f32x4;
typedef __attribute__((ext_vector_type(4))) unsigned short u16x4;
typedef __attribute__((ext_vector_type(8))) unsigned short u16x8;
typedef __attribute__((ext_vector_type(4))) int i32x4;

typedef const void __attribute__((address_space(1)))* gas_t;
typedef void __attribute__((address_space(3)))* las_t;

__device__ __forceinline__ u16 f2bf(float x) {
  unsigned u = __float_as_uint(x);
  return (u16)((u + 0x7FFFu + ((u >> 16) & 1)) >> 16);  // RNE
}

// ---------------- K1 fused: maskT-role (1024 blocks) + h-role (256 blocks) ----------------
// maskT: adj -> maskT bf16 [i][j] = (j<4095 && adj[j+1][i]>0)   (conflict-free LDS transpose)
// h-role: h = inp@W^T + b (bf16 MFMA) -> h2t bf16 K-major; p1[b,i] = h.a1 in-register;
//         hpart per-block hsum partial (4-wave LDS reduce — round-7 bug was a 4-wave race);
//         zeroes s slice for the gemm's atomics.
__global__ __launch_bounds__(256) void k_prep(const int* __restrict__ adj, const float* __restrict__ inp,
                                              const float* __restrict__ Ww, const float* __restrict__ Wb,
                                              const float* __restrict__ a, u16* __restrict__ maskT,
                                              u16* __restrict__ h2t, float* __restrict__ p1,
                                              float* __restrict__ hpart, float* __restrict__ s) {
  __shared__ __align__(16) char Lraw[33792];  // union: maskT tile (33792 B) | lA(16384)+lW(8192)
  __shared__ float wsum[4][64];
  const int bid = blockIdx.x;
  const int t = threadIdx.x;

  if (bid < 1024) {
    // ---- maskT role ----
    u16* tile = (u16*)Lraw;  // [j-row][i-col swizzled], stride 132 u16
    const int i0 = (bid & 31) * 128, j0 = (bid >> 5) * 128;
    const int jr = t >> 5;   // row-within-8
    const int il = t & 31;   // col-block 0..31
#pragma unroll
    for (int pass = 0; pass < 16; ++pass) {
      const int jl = pass * 8 + jr;
      const int j = j0 + jl;
      u16 q[4] = {0, 0, 0, 0};
      if (j < NN - 1) {
        i32x4 av = *reinterpret_cast<const i32x4*>(&adj[(size_t)(j + 1) * NN + i0 + il * 4]);
        q[0] = av.x > 0 ? 0x3F80 : 0;
        q[1] = av.y > 0 ? 0x3F80 : 0;
        q[2] = av.z > 0 ? 0x3F80 : 0;
        q[3] = av.w > 0 ? 0x3F80 : 0;
      }
      const int pb = il ^ (jl >> 2);
      *reinterpret_cast<u16x4*>(&tile[jl * 132 + pb * 4]) = *reinterpret_cast<u16x4*>(q);
    }
    __syncthreads();
#pragma unroll
    for (int pass = 0; pass < 16; ++pass) {
      const int ir = pass * 8 + jr;
      const int ci = ir >> 2, io = ir & 3;
      u16 o[4];
#pragma unroll
      for (int d = 0; d < 4; ++d) {
        const int r = il * 4 + d;
        o[d] = tile[r * 132 + ((ci ^ il) << 2) + io];
      }
      *reinterpret_cast<u16x4*>(&maskT[(size_t)(i0 + ir) * NN + j0 + il * 4]) =
          *reinterpret_cast<u16x4*>(o);
    }
    return;
  }

  // ---- h role ----
  u16* lA = (u16*)Lraw;            // [128][64] bf16, XOR-swizzled
  u16* lW = (u16*)(Lraw + 16384);  // [64][64]
  const int hb = bid - 1024;       // 0..255
  const int lane = t & 63, w = t >> 6;
  const int b = hb >> 5;
  const size_t row0 = (size_t)hb * 128;
  if (t < 128) s[hb * 128 + t] = 0.f;  // zero the gemm's accumulator slice
  {
    const int o = t >> 2, k0 = (t & 3) * 16;
    const float* src = &Ww[o * 64 + k0];
    u16 tmp[16];
#pragma unroll
    for (int e = 0; e < 16; ++e) tmp[e] = f2bf(src[e]);
    const int swz = (o & 7) * 8;
#pragma unroll
    for (int v = 0; v < 2; ++v)
      *reinterpret_cast<u16x8*>(&lW[o * 64 + ((k0 + v * 8) ^ swz)]) = *reinterpret_cast<u16x8*>(&tmp[v * 8]);
  }
  {
    const int r = t >> 1, k0 = (t & 1) * 32;
    const float* src = &inp[(row0 + r) * 64 + k0];
    u16 tmp[32];
#pragma unroll
    for (int e = 0; e < 32; ++e) tmp[e] = f2bf(src[e]);
    const int swz = (r & 7) * 8;
#pragma unroll
    for (int v = 0; v < 4; ++v)
      *reinterpret_cast<u16x8*>(&lA[r * 64 + ((k0 + v * 8) ^ swz)]) = *reinterpret_cast<u16x8*>(&tmp[v * 8]);
  }
  __syncthreads();
  f32x4 acc[2][4] = {};
#pragma unroll
  for (int ks = 0; ks < 2; ++ks) {
    const int kk = ks * 32 + (lane >> 4) * 8;
    short8 af[2], bf[4];
#pragma unroll
    for (int m = 0; m < 2; ++m) {
      const int row = w * 32 + m * 16 + (lane & 15);
      af[m] = *reinterpret_cast<const short8*>(&lA[row * 64 + (kk ^ ((row & 7) * 8))]);
    }
#pragma unroll
    for (int n = 0; n < 4; ++n) {
      const int o = n * 16 + (lane & 15);
      bf[n] = *reinterpret_cast<const short8*>(&lW[o * 64 + (kk ^ ((o & 7) * 8))]);
    }
#pragma unroll
    for (int m = 0; m < 2; ++m)
#pragma unroll
      for (int n = 0; n < 4; ++n)
        acc[m][n] = __builtin_amdgcn_mfma_f32_16x16x32_bf16(af[m], bf[n], acc[m][n], 0, 0, 0);
  }
  // epilogue: bias + row-0 zero; h2t bf16 store; p1 = h.a1 (in-register); hpart via LDS reduce
  const int f0 = lane & 15;
  const int rsub = (lane >> 4) * 4;
  float wb[4];
#pragma unroll
  for (int n = 0; n < 4; ++n) wb[n] = Wb[n * 16 + f0];
  const int nloc_base = (hb & 31) * 128;
  float ps[4] = {0.f, 0.f, 0.f, 0.f};
#pragma unroll
  for (int m = 0; m < 2; ++m) {
    const int rl = w * 32 + m * 16 + rsub;
    float vz[4][4];
#pragma unroll
    for (int n = 0; n < 4; ++n) {
      u16 hb4[4];
#pragma unroll
      for (int r = 0; r < 4; ++r) {
        float v = acc[m][n][r] + wb[n];
        if (nloc_base + rl + r == 0) v = 0.f;
        vz[n][r] = v;
        hb4[r] = f2bf(v);
        ps[n] += v;
      }
      *reinterpret_cast<u16x4*>(&h2t[(size_t)(b * 64 + n * 16 + f0) * NN + nloc_base + rl]) =
          *reinterpret_cast<u16x4*>(&hb4[0]);
    }
#pragma unroll
    for (int r = 0; r < 4; ++r) {
      const int ig = nloc_base + rl + r;  // node index within batch
      float pv = 0.f;
#pragma unroll
      for (int n = 0; n < 4; ++n) pv += vz[n][r] * a[(size_t)(n * 16 + f0) * NN + ig];
      pv += __shfl_xor(pv, 1);
      pv += __shfl_xor(pv, 2);
      pv += __shfl_xor(pv, 4);
      pv += __shfl_xor(pv, 8);
      if (f0 == 0) p1[(size_t)b * NN + ig] = pv;
    }
  }
  // per-wave partial -> LDS -> single per-block hpart slot (fixes round-7 4-wave race)
#pragma unroll
  for (int n = 0; n < 4; ++n) {
    float v = ps[n];
    v += __shfl_xor(v, 16);
    v += __shfl_xor(v, 32);
    if (lane < 16) wsum[w][n * 16 + f0] = v;
  }
  __syncthreads();
  if (t < 64) hpart[hb * 64 + t] = wsum[0][t] + wsum[1][t] + wsum[2][t] + wsum[3][t];
}

// ---------------- K2: fused GEMM, counted-vmcnt double-buffered pipeline (unchanged) ----------------
__global__ __launch_bounds__(256, 2) void k_gemm(const u16* __restrict__ A, const u16* __restrict__ Bm,
                                                 const float* __restrict__ a, float* __restrict__ s) {
  __shared__ __align__(16) u16 lA0[128 * 64], lA1[128 * 64];
  __shared__ __align__(16) u16 lB0[128 * 64], lB1[128 * 64];
  const int sid = blockIdx.x;                       // 0..511
  const int wgid = (sid & 7) * 64 + (sid >> 3);     // bijective XCD-chunk swizzle
  const int c0 = (wgid & 3) * 128;
  const int i0 = ((wgid >> 2) & 31) * 128;
  const int z = wgid >> 7;                          // 0..3
  const int t = threadIdx.x, lane = t & 63, w = t >> 6;
  const int wr = w >> 1, wc = w & 1;

  const int srow = lane >> 3;
  const int sk = ((lane & 7) ^ srow) * 8;           // pre-swizzled source k-offset
  const size_t kbase = (size_t)z * 1024;
  const u16* gA = A + (size_t)(i0 + w * 32 + srow) * NN + kbase + sk;
  const u16* gB = Bm + (size_t)(c0 + w * 32 + srow) * NN + kbase + sk;

#define STAGE_K(dstA, dstB, kt)                                                              \
  do {                                                                                       \
    _Pragma("unroll") for (int c = 0; c < 4; ++c) {                                          \
      __builtin_amdgcn_global_load_lds((gas_t)(gA + (size_t)(8 * c) * NN + (kt)),            \
                                       (las_t)((dstA) + (w * 32 + 8 * c) * 128 + lane * 16), \
                                       16, 0, 0);                                            \
      __builtin_amdgcn_global_load_lds((gas_t)(gB + (size_t)(8 * c) * NN + (kt)),            \
                                       (las_t)((dstB) + (w * 32 + 8 * c) * 128 + lane * 16), \
                                       16, 0, 0);                                            \
    }                                                                                        \
  } while (0)

  f32x4 acc[4][4] = {};
  asm volatile("" ::: "memory");
  STAGE_K((char*)lA0, (char*)lB0, 0);
#pragma unroll 1
  for (int it = 0; it < 16; ++it) {
    char* nA = (it & 1) ? (char*)lA0 : (char*)lA1;
    char* nB = (it & 1) ? (char*)lB0 : (char*)lB1;
    if (it < 15) {
      STAGE_K(nA, nB, (it + 1) * 64);
      asm volatile("s_waitcnt vmcnt(8)" ::: "memory");
    } else {
      asm volatile("s_waitcnt vmcnt(0)" ::: "memory");
    }
    __builtin_amdgcn_s_barrier();
    asm volatile("" ::: "memory");
    const u16* cA = (it & 1) ? lA1 : lA0;
    const u16* cB = (it & 1) ? lB1 : lB0;
#pragma unroll
    for (int ks = 0; ks < 2; ++ks) {
      const int kb = ks * 4 + (lane >> 4);
      short8 af[4], bfr[4];
#pragma unroll
      for (int m = 0; m < 4; ++m) {
        const int row = wr * 64 + m * 16 + (lane & 15);
        af[m] = *reinterpret_cast<const short8*>(&cA[row * 64 + ((kb ^ (row & 7)) * 8)]);
      }
#pragma unroll
      for (int n = 0; n < 4; ++n) {
        const int row = wc * 64 + n * 16 + (lane & 15);
        bfr[n] = *reinterpret_cast<const short8*>(&cB[row * 64 + ((kb ^ (row & 7)) * 8)]);
      }
#pragma unroll
      for (int m = 0; m < 4; ++m)
#pragma unroll
        for (int n = 0; n < 4; ++n)
          acc[m][n] = __builtin_amdgcn_mfma_f32_16x16x32_bf16(af[m], bfr[n], acc[m][n], 0, 0, 0);
    }
    asm volatile("" ::: "memory");
    __builtin_amdgcn_s_barrier();
  }
#undef STAGE_K
  const int b = (c0 >> 7) * 2 + wc;
  const int f0 = lane & 15, rsub = (lane >> 4) * 4;
  float pp[4][4];
#pragma unroll
  for (int m = 0; m < 4; ++m) {
    const int irow = i0 + wr * 64 + m * 16 + rsub;
#pragma unroll
    for (int r = 0; r < 4; ++r) pp[m][r] = 0.f;
#pragma unroll
    for (int n = 0; n < 4; ++n) {
      f32x4 a2v = *reinterpret_cast<const f32x4*>(&a[(size_t)(64 + n * 16 + f0) * NN + irow]);
#pragma unroll
      for (int r = 0; r < 4; ++r) pp[m][r] += acc[m][n][r] * a2v[r];
    }
  }
#pragma unroll
  for (int m = 0; m < 4; ++m)
#pragma unroll
    for (int r = 0; r < 4; ++r) {
      float v = pp[m][r];
      v += __shfl_xor(v, 1);
      v += __shfl_xor(v, 2);
      v += __shfl_xor(v, 4);
      v += __shfl_xor(v, 8);
      pp[m][r] = v;
    }
  if (f0 == 0) {
    const int irow = i0 + wr * 64 + rsub;
#pragma unroll
    for (int m = 0; m < 4; ++m)
#pragma unroll
      for (int r = 0; r < 4; ++r)
        atomicAdd(&s[(size_t)b * NN + irow + m * 16 + r], pp[m][r]);
  }
}

// ---------------- K3: out = lrelu((p1 + s) * hsum), hsum reduced from hpart ----------------
__global__ __launch_bounds__(256) void k_final(const float* __restrict__ p1, const float* __restrict__ sg,
                                               const float* __restrict__ hpart, float* __restrict__ out) {
  __shared__ float hp[4][64];
  __shared__ float hs[64], sv[64];
  const int b = blockIdx.x >> 6;
  const int i0 = (blockIdx.x & 63) * 64;
  const int t = threadIdx.x;
  {
    const int f = t & 63, g = t >> 6;
    float acc = 0.f;
#pragma unroll
    for (int sl = 0; sl < 8; ++sl) acc += hpart[(size_t)(b * 32 + g * 8 + sl) * 64 + f];
    hp[g][f] = acc;
  }
  __syncthreads();
  if (t < 64) {
    hs[t] = hp[0][t] + hp[1][t] + hp[2][t] + hp[3][t];
    const int i = i0 + t;
    sv[t] = (i == 0) ? 0.f : (p1[(size_t)b * NN + i] + sg[(size_t)b * NN + i]);
  }
  __syncthreads();
  const int fq = (t & 15) * 4, ir = t >> 4;
#pragma unroll
  for (int pass = 0; pass < 4; ++pass) {
    const int ii = pass * 16 + ir;
    const float svi = sv[ii];
    f32x4 o;
#pragma unroll
    for (int k = 0; k < 4; ++k) {
      float val = svi * hs[fq + k];
      o[k] = (val >= 0.f) ? val : 0.01f * val;
    }
    *reinterpret_cast<f32x4*>(&out[((size_t)b * NN + i0 + ii) * 64 + fq]) = o;
  }
}

extern "C" void kernel_launch(void* const* d_in, const int* in_sizes, int n_in,
                              void* d_out, int out_size, void* d_ws, size_t ws_size,
                              hipStream_t stream) {
  const float* inp = (const float*)d_in[0];
  const int* adj = (const int*)d_in[1];
  const float* Ww = (const float*)d_in[2];
  const float* Wb = (const float*)d_in[3];
  const float* a = (const float*)d_in[4];
  float* out = (float*)d_out;
  char* ws = (char*)d_ws;

  float* s = (float*)ws;                         // 128 KB [8][4096]
  float* hpart = (float*)(ws + 131072);          //  64 KB [256][64]
  float* p1 = (float*)(ws + 196608);             // 128 KB [8][4096]
  u16* maskT = (u16*)(ws + 524288);              //  32 MB [4096][4096] bf16
  u16* h2t = (u16*)(ws + 524288 + 33554432);     //   4 MB [512][4096] bf16

  hipLaunchKernelGGL(k_prep, dim3(1280), dim3(256), 0, stream, adj, inp, Ww, Wb, a,
                     maskT, h2t, p1, hpart, s);
  hipLaunchKernelGGL(k_gemm, dim3(512), dim3(256), 0, stream, maskT, h2t, a, s);
  hipLaunchKernelGGL(k_final, dim3(512), dim3(256), 0, stream, p1, s, hpart, out);
}

// Round 9
// 142.607 us; speedup vs baseline: 1.0769x; 1.0769x over previous
//
#include <hip/hip_runtime.h>
#include <hip/hip_bf16.h>

#define NN 4096

typedef unsigned short u16;
typedef __attribute__((ext_vector_type(8))) short short8;
typedef __attribute__((ext_vector_type(4))) float f32x4;
typedef __attribute__((ext_vector_type(4))) unsigned short u16x4;
typedef __attribute__((ext_vector_type(8))) unsigned short u16x8;
typedef __attribute__((ext_vector_type(4))) int i32x4;

typedef const void __attribute__((address_space(1)))* gas_t;
typedef void __attribute__((address_space(3)))* las_t;

__device__ __forceinline__ u16 f2bf(float x) {
  unsigned u = __float_as_uint(x);
  return (u16)((u + 0x7FFFu + ((u >> 16) & 1)) >> 16);  // RNE
}

// ---------------- K1 fused: bitmask-role (1024 blocks) + h-role (256 blocks) ----------------
// bitmask: adj -> AbitsT[jw][i], bit p of word (jw,i) = (j=jw*32+p < 4095 && adj[j+1][i]>0).
//   Pure-register transpose: 16 ILP'd loads -> 16-bit packs -> shfl_xor(32) pairing -> coalesced
//   u32x4 stores. 2 MB output (was 32 MB bf16), no LDS, no barrier.
// h-role: h = inp@W^T + b (bf16 MFMA) -> h2t bf16 K-major; p1 = h.a1 in-register; hpart; zeros s.
__global__ __launch_bounds__(256) void k_prep(const int* __restrict__ adj, const float* __restrict__ inp,
                                              const float* __restrict__ Ww, const float* __restrict__ Wb,
                                              const float* __restrict__ a, unsigned* __restrict__ AbitsT,
                                              u16* __restrict__ h2t, float* __restrict__ p1,
                                              float* __restrict__ hpart, float* __restrict__ s) {
  __shared__ __align__(16) char Lraw[24576];  // h-role only: lA(16384)+lW(8192)
  __shared__ float wsum[4][64];
  const int bid = blockIdx.x;
  const int t = threadIdx.x;

  if (bid < 1024) {
    // ---- bitmask role ----
    const int i0 = (bid & 31) * 128, j0 = (bid >> 5) * 128;
    const int jr = t >> 5, il = t & 31;   // thread: j-rows j0+jr*16..+15, i-quad i0+il*4..+3
    i32x4 av[16];
#pragma unroll
    for (int p = 0; p < 16; ++p) {
      const int j = j0 + jr * 16 + p;
      if (j < NN - 1)
        av[p] = *reinterpret_cast<const i32x4*>(&adj[(size_t)(j + 1) * NN + i0 + il * 4]);
      else
        av[p] = i32x4{0, 0, 0, 0};
    }
    unsigned accb[4] = {0, 0, 0, 0};
#pragma unroll
    for (int p = 0; p < 16; ++p)
#pragma unroll
      for (int d = 0; d < 4; ++d)
        accb[d] |= (av[p][d] > 0 ? 1u : 0u) << p;
    unsigned wout[4];
#pragma unroll
    for (int d = 0; d < 4; ++d) {
      unsigned part = (unsigned)__shfl_xor((int)accb[d], 32);  // partner jr^1
      wout[d] = accb[d] | (part << 16);
    }
    if ((jr & 1) == 0) {  // even jr holds low half -> owns word (j0>>5)+(jr>>1)
      const int jw = (j0 >> 5) + (jr >> 1);
      *reinterpret_cast<i32x4*>(&AbitsT[(size_t)jw * NN + i0 + il * 4]) =
          *reinterpret_cast<i32x4*>(wout);
    }
    return;
  }

  // ---- h role (unchanged from round 8) ----
  u16* lA = (u16*)Lraw;            // [128][64] bf16, XOR-swizzled
  u16* lW = (u16*)(Lraw + 16384);  // [64][64]
  const int hb = bid - 1024;       // 0..255
  const int lane = t & 63, w = t >> 6;
  const int b = hb >> 5;
  const size_t row0 = (size_t)hb * 128;
  if (t < 128) s[hb * 128 + t] = 0.f;  // zero the gemm's accumulator slice
  {
    const int o = t >> 2, k0 = (t & 3) * 16;
    const float* src = &Ww[o * 64 + k0];
    u16 tmp[16];
#pragma unroll
    for (int e = 0; e < 16; ++e) tmp[e] = f2bf(src[e]);
    const int swz = (o & 7) * 8;
#pragma unroll
    for (int v = 0; v < 2; ++v)
      *reinterpret_cast<u16x8*>(&lW[o * 64 + ((k0 + v * 8) ^ swz)]) = *reinterpret_cast<u16x8*>(&tmp[v * 8]);
  }
  {
    const int r = t >> 1, k0 = (t & 1) * 32;
    const float* src = &inp[(row0 + r) * 64 + k0];
    u16 tmp[32];
#pragma unroll
    for (int e = 0; e < 32; ++e) tmp[e] = f2bf(src[e]);
    const int swz = (r & 7) * 8;
#pragma unroll
    for (int v = 0; v < 4; ++v)
      *reinterpret_cast<u16x8*>(&lA[r * 64 + ((k0 + v * 8) ^ swz)]) = *reinterpret_cast<u16x8*>(&tmp[v * 8]);
  }
  __syncthreads();
  f32x4 acc[2][4] = {};
#pragma unroll
  for (int ks = 0; ks < 2; ++ks) {
    const int kk = ks * 32 + (lane >> 4) * 8;
    short8 af[2], bf[4];
#pragma unroll
    for (int m = 0; m < 2; ++m) {
      const int row = w * 32 + m * 16 + (lane & 15);
      af[m] = *reinterpret_cast<const short8*>(&lA[row * 64 + (kk ^ ((row & 7) * 8))]);
    }
#pragma unroll
    for (int n = 0; n < 4; ++n) {
      const int o = n * 16 + (lane & 15);
      bf[n] = *reinterpret_cast<const short8*>(&lW[o * 64 + (kk ^ ((o & 7) * 8))]);
    }
#pragma unroll
    for (int m = 0; m < 2; ++m)
#pragma unroll
      for (int n = 0; n < 4; ++n)
        acc[m][n] = __builtin_amdgcn_mfma_f32_16x16x32_bf16(af[m], bf[n], acc[m][n], 0, 0, 0);
  }
  const int f0 = lane & 15;
  const int rsub = (lane >> 4) * 4;
  float wb[4];
#pragma unroll
  for (int n = 0; n < 4; ++n) wb[n] = Wb[n * 16 + f0];
  const int nloc_base = (hb & 31) * 128;
  float ps[4] = {0.f, 0.f, 0.f, 0.f};
#pragma unroll
  for (int m = 0; m < 2; ++m) {
    const int rl = w * 32 + m * 16 + rsub;
    float vz[4][4];
#pragma unroll
    for (int n = 0; n < 4; ++n) {
      u16 hb4[4];
#pragma unroll
      for (int r = 0; r < 4; ++r) {
        float v = acc[m][n][r] + wb[n];
        if (nloc_base + rl + r == 0) v = 0.f;
        vz[n][r] = v;
        hb4[r] = f2bf(v);
        ps[n] += v;
      }
      *reinterpret_cast<u16x4*>(&h2t[(size_t)(b * 64 + n * 16 + f0) * NN + nloc_base + rl]) =
          *reinterpret_cast<u16x4*>(&hb4[0]);
    }
#pragma unroll
    for (int r = 0; r < 4; ++r) {
      const int ig = nloc_base + rl + r;
      float pv = 0.f;
#pragma unroll
      for (int n = 0; n < 4; ++n) pv += vz[n][r] * a[(size_t)(n * 16 + f0) * NN + ig];
      pv += __shfl_xor(pv, 1);
      pv += __shfl_xor(pv, 2);
      pv += __shfl_xor(pv, 4);
      pv += __shfl_xor(pv, 8);
      if (f0 == 0) p1[(size_t)b * NN + ig] = pv;
    }
  }
#pragma unroll
  for (int n = 0; n < 4; ++n) {
    float v = ps[n];
    v += __shfl_xor(v, 16);
    v += __shfl_xor(v, 32);
    if (lane < 16) wsum[w][n * 16 + f0] = v;
  }
  __syncthreads();
  if (t < 64) hpart[hb * 64 + t] = wsum[0][t] + wsum[1][t] + wsum[2][t] + wsum[3][t];
}

// ---------------- K2: fused GEMM, bit-A (nibble LUT) + counted-vmcnt dbuf pipeline ----------------
// s[b,i] += sum_f a2[f,i] * sum_j mask(i,j)*h2t[b*64+f,j]
// A from AbitsT: 1 KB bits per K-step (1 gload_lds), LUT-expanded to bf16 fragments.
// LDS 34.9 KB -> 4 blocks/CU (was 2). B-path/pipeline/epilogue unchanged from round 8.
__global__ __launch_bounds__(256, 4) void k_gemm(const unsigned* __restrict__ Ab, const u16* __restrict__ Bm,
                                                 const float* __restrict__ a, float* __restrict__ s) {
  __shared__ __align__(16) u16 lB0[128 * 64], lB1[128 * 64];
  __shared__ __align__(16) unsigned lAb0[256], lAb1[256];
  __shared__ __align__(16) u16 lut[16][4];
  const int sid = blockIdx.x;                       // 0..511
  const int wgid = (sid & 7) * 64 + (sid >> 3);     // bijective XCD-chunk swizzle
  const int c0 = (wgid & 3) * 128;
  const int i0 = ((wgid >> 2) & 31) * 128;
  const int z = wgid >> 7;                          // 0..3
  const int t = threadIdx.x, lane = t & 63, w = t >> 6;
  const int wr = w >> 1, wc = w & 1;
  if (t < 16) {
    lut[t][0] = (t & 1) ? 0x3F80 : 0;
    lut[t][1] = (t & 2) ? 0x3F80 : 0;
    lut[t][2] = (t & 4) ? 0x3F80 : 0;
    lut[t][3] = (t & 8) ? 0x3F80 : 0;
  }

  const int srow = lane >> 3;
  const int sk = ((lane & 7) ^ srow) * 8;           // pre-swizzled source k-offset (B only)
  const size_t kbase = (size_t)z * 1024;
  const u16* gB = Bm + (size_t)(c0 + w * 32 + srow) * NN + kbase + sk;
  // A-bits source: lane l -> word-row z*32 + it*2 + (l>>5), i = i0 + (l&31)*4 (16 B each)
  const unsigned* gAb = Ab + (size_t)(z * 32 + (lane >> 5)) * NN + i0 + (lane & 31) * 4;

#define STAGE_K(dstB, dstA, it_)                                                             \
  do {                                                                                       \
    __builtin_amdgcn_global_load_lds((gas_t)(gAb + (size_t)(it_) * 2 * NN),                  \
                                     (las_t)((char*)(dstA) + lane * 16), 16, 0, 0);          \
    _Pragma("unroll") for (int c = 0; c < 4; ++c) {                                          \
      __builtin_amdgcn_global_load_lds((gas_t)(gB + (size_t)(8 * c) * NN + (it_) * 64),      \
                                       (las_t)((char*)(dstB) + (w * 32 + 8 * c) * 128 + lane * 16), \
                                       16, 0, 0);                                            \
    }                                                                                        \
  } while (0)

  f32x4 acc[4][4] = {};
  asm volatile("" ::: "memory");
  STAGE_K(lB0, lAb0, 0);   // 5 loads/lane in flight
#pragma unroll 1
  for (int it = 0; it < 16; ++it) {
    if (it < 15) {
      if (it & 1) STAGE_K(lB0, lAb0, it + 1); else STAGE_K(lB1, lAb1, it + 1);  // +5 (tile t+1)
      asm volatile("s_waitcnt vmcnt(5)" ::: "memory");     // drain tile t only
    } else {
      asm volatile("s_waitcnt vmcnt(0)" ::: "memory");
    }
    __builtin_amdgcn_s_barrier();                          // all waves: tile t resident
    asm volatile("" ::: "memory");
    const u16* cB = (it & 1) ? lB1 : lB0;
    const unsigned* cAb = (it & 1) ? lAb1 : lAb0;
    const int q = lane >> 4;
#pragma unroll
    for (int ks = 0; ks < 2; ++ks) {
      short8 af[4], bfr[4];
#pragma unroll
      for (int m = 0; m < 4; ++m) {
        const unsigned wrd = cAb[ks * 128 + wr * 64 + m * 16 + (lane & 15)];  // broadcast over q
        const unsigned b8 = (wrd >> (q * 8)) & 0xFFu;
        union { unsigned long long qq[2]; short8 s8; } u;
        u.qq[0] = *reinterpret_cast<const unsigned long long*>(&lut[b8 & 15][0]);
        u.qq[1] = *reinterpret_cast<const unsigned long long*>(&lut[b8 >> 4][0]);
        af[m] = u.s8;
      }
#pragma unroll
      for (int n = 0; n < 4; ++n) {
        const int row = wc * 64 + n * 16 + (lane & 15);
        const int kb = ks * 4 + q;
        bfr[n] = *reinterpret_cast<const short8*>(&cB[row * 64 + ((kb ^ (row & 7)) * 8)]);
      }
#pragma unroll
      for (int m = 0; m < 4; ++m)
#pragma unroll
        for (int n = 0; n < 4; ++n)
          acc[m][n] = __builtin_amdgcn_mfma_f32_16x16x32_bf16(af[m], bfr[n], acc[m][n], 0, 0, 0);
    }
    asm volatile("" ::: "memory");
    __builtin_amdgcn_s_barrier();                          // buffer-reuse protection
  }
#undef STAGE_K
  // fused epilogue: contract cols (f) with a2[f][i], reduce over f-lanes, atomicAdd into s
  const int b = (c0 >> 7) * 2 + wc;
  const int f0 = lane & 15, rsub = (lane >> 4) * 4;
  float pp[4][4];
#pragma unroll
  for (int m = 0; m < 4; ++m) {
    const int irow = i0 + wr * 64 + m * 16 + rsub;
#pragma unroll
    for (int r = 0; r < 4; ++r) pp[m][r] = 0.f;
#pragma unroll
    for (int n = 0; n < 4; ++n) {
      f32x4 a2v = *reinterpret_cast<const f32x4*>(&a[(size_t)(64 + n * 16 + f0) * NN + irow]);
#pragma unroll
      for (int r = 0; r < 4; ++r) pp[m][r] += acc[m][n][r] * a2v[r];
    }
  }
#pragma unroll
  for (int m = 0; m < 4; ++m)
#pragma unroll
    for (int r = 0; r < 4; ++r) {
      float v = pp[m][r];
      v += __shfl_xor(v, 1);
      v += __shfl_xor(v, 2);
      v += __shfl_xor(v, 4);
      v += __shfl_xor(v, 8);
      pp[m][r] = v;
    }
  if (f0 == 0) {
    const int irow = i0 + wr * 64 + rsub;
#pragma unroll
    for (int m = 0; m < 4; ++m)
#pragma unroll
      for (int r = 0; r < 4; ++r)
        atomicAdd(&s[(size_t)b * NN + irow + m * 16 + r], pp[m][r]);
  }
}

// ---------------- K3: out = lrelu((p1 + s) * hsum), hsum reduced from hpart ----------------
__global__ __launch_bounds__(256) void k_final(const float* __restrict__ p1, const float* __restrict__ sg,
                                               const float* __restrict__ hpart, float* __restrict__ out) {
  __shared__ float hp[4][64];
  __shared__ float hs[64], sv[64];
  const int b = blockIdx.x >> 6;
  const int i0 = (blockIdx.x & 63) * 64;
  const int t = threadIdx.x;
  {
    const int f = t & 63, g = t >> 6;
    float acc = 0.f;
#pragma unroll
    for (int sl = 0; sl < 8; ++sl) acc += hpart[(size_t)(b * 32 + g * 8 + sl) * 64 + f];
    hp[g][f] = acc;
  }
  __syncthreads();
  if (t < 64) {
    hs[t] = hp[0][t] + hp[1][t] + hp[2][t] + hp[3][t];
    const int i = i0 + t;
    sv[t] = (i == 0) ? 0.f : (p1[(size_t)b * NN + i] + sg[(size_t)b * NN + i]);
  }
  __syncthreads();
  const int fq = (t & 15) * 4, ir = t >> 4;
#pragma unroll
  for (int pass = 0; pass < 4; ++pass) {
    const int ii = pass * 16 + ir;
    const float svi = sv[ii];
    f32x4 o;
#pragma unroll
    for (int k = 0; k < 4; ++k) {
      float val = svi * hs[fq + k];
      o[k] = (val >= 0.f) ? val : 0.01f * val;
    }
    *reinterpret_cast<f32x4*>(&out[((size_t)b * NN + i0 + ii) * 64 + fq]) = o;
  }
}

extern "C" void kernel_launch(void* const* d_in, const int* in_sizes, int n_in,
                              void* d_out, int out_size, void* d_ws, size_t ws_size,
                              hipStream_t stream) {
  const float* inp = (const float*)d_in[0];
  const int* adj = (const int*)d_in[1];
  const float* Ww = (const float*)d_in[2];
  const float* Wb = (const float*)d_in[3];
  const float* a = (const float*)d_in[4];
  float* out = (float*)d_out;
  char* ws = (char*)d_ws;

  float* s = (float*)ws;                          // 128 KB [8][4096]
  float* hpart = (float*)(ws + 131072);           //  64 KB [256][64]
  float* p1 = (float*)(ws + 196608);              // 128 KB [8][4096]
  unsigned* AbitsT = (unsigned*)(ws + 524288);    //   2 MB [128 jwords][4096 i]
  u16* h2t = (u16*)(ws + 524288 + 2097152);       //   4 MB [512][4096] bf16

  hipLaunchKernelGGL(k_prep, dim3(1280), dim3(256), 0, stream, adj, inp, Ww, Wb, a,
                     AbitsT, h2t, p1, hpart, s);
  hipLaunchKernelGGL(k_gemm, dim3(512), dim3(256), 0, stream, AbitsT, h2t, a, s);
  hipLaunchKernelGGL(k_final, dim3(512), dim3(256), 0, stream, p1, s, hpart, out);
}

// Round 10
// 138.683 us; speedup vs baseline: 1.1073x; 1.0283x over previous
//
#include <hip/hip_runtime.h>
#include <hip/hip_bf16.h>

#define NN 4096

typedef unsigned short u16;
typedef __attribute__((ext_vector_type(8))) short short8;
typedef __attribute__((ext_vector_type(4))) float f32x4;
typedef __attribute__((ext_vector_type(4))) unsigned short u16x4;
typedef __attribute__((ext_vector_type(8))) unsigned short u16x8;
typedef __attribute__((ext_vector_type(4))) int i32x4;

typedef const void __attribute__((address_space(1)))* gas_t;
typedef void __attribute__((address_space(3)))* las_t;

__device__ __forceinline__ u16 f2bf(float x) {
  unsigned u = __float_as_uint(x);
  return (u16)((u + 0x7FFFu + ((u >> 16) & 1)) >> 16);  // RNE
}

// ---------------- K1 fused: bitmask-role (1024 blocks) + h-role (256 blocks) ----------------
// bitmask: adj -> AbitsT[jw][i], bit p of word (jw,i) = (j=jw*32+p < 4095 && adj[j+1][i]>0).
//   Register transpose, 2x8-batched ILP loads (VGPR-capped), boundary predicate hoisted to
//   block level. 2 MB output, no LDS, no barrier.
// h-role: h = inp@W^T + b (bf16 MFMA) -> h2t bf16 K-major; p1 = h.a1 in-register; hpart; zeros s.
__global__ __launch_bounds__(256) void k_prep(const int* __restrict__ adj, const float* __restrict__ inp,
                                              const float* __restrict__ Ww, const float* __restrict__ Wb,
                                              const float* __restrict__ a, unsigned* __restrict__ AbitsT,
                                              u16* __restrict__ h2t, float* __restrict__ p1,
                                              float* __restrict__ hpart, float* __restrict__ s) {
  __shared__ __align__(16) char Lraw[24576];  // h-role only: lA(16384)+lW(8192)
  __shared__ float wsum[4][64];
  const int bid = blockIdx.x;
  const int t = threadIdx.x;

  if (bid < 1024) {
    // ---- bitmask role ----
    const int i0 = (bid & 31) * 128, j0 = (bid >> 5) * 128;
    const int jr = t >> 5, il = t & 31;   // thread: j-rows j0+jr*16..+15, i-quad i0+il*4..+3
    const int jbase = j0 + jr * 16;
    unsigned accb[4] = {0, 0, 0, 0};
    if (j0 + 128 <= NN - 1) {
      // interior: all 16 rows valid (j <= j0+127 <= 4094)
#pragma unroll
      for (int h = 0; h < 2; ++h) {
        i32x4 av[8];
#pragma unroll
        for (int p = 0; p < 8; ++p)
          av[p] = *reinterpret_cast<const i32x4*>(&adj[(size_t)(jbase + h * 8 + p + 1) * NN + i0 + il * 4]);
#pragma unroll
        for (int p = 0; p < 8; ++p)
#pragma unroll
          for (int d = 0; d < 4; ++d)
            accb[d] |= (av[p][d] > 0 ? 1u : 0u) << (h * 8 + p);
      }
    } else {
      // last j-block: predicate per row
#pragma unroll
      for (int h = 0; h < 2; ++h) {
        i32x4 av[8];
#pragma unroll
        for (int p = 0; p < 8; ++p) {
          const int j = jbase + h * 8 + p;
          if (j < NN - 1)
            av[p] = *reinterpret_cast<const i32x4*>(&adj[(size_t)(j + 1) * NN + i0 + il * 4]);
          else
            av[p] = i32x4{0, 0, 0, 0};
        }
#pragma unroll
        for (int p = 0; p < 8; ++p)
#pragma unroll
          for (int d = 0; d < 4; ++d)
            accb[d] |= (av[p][d] > 0 ? 1u : 0u) << (h * 8 + p);
      }
    }
    unsigned wout[4];
#pragma unroll
    for (int d = 0; d < 4; ++d) {
      unsigned part = (unsigned)__shfl_xor((int)accb[d], 32);  // partner jr^1
      wout[d] = accb[d] | (part << 16);
    }
    if ((jr & 1) == 0) {  // even jr owns word (j0>>5)+(jr>>1)
      const int jw = (j0 >> 5) + (jr >> 1);
      *reinterpret_cast<i32x4*>(&AbitsT[(size_t)jw * NN + i0 + il * 4]) =
          *reinterpret_cast<i32x4*>(wout);
    }
    return;
  }

  // ---- h role (unchanged) ----
  u16* lA = (u16*)Lraw;            // [128][64] bf16, XOR-swizzled
  u16* lW = (u16*)(Lraw + 16384);  // [64][64]
  const int hb = bid - 1024;       // 0..255
  const int lane = t & 63, w = t >> 6;
  const int b = hb >> 5;
  const size_t row0 = (size_t)hb * 128;
  if (t < 128) s[hb * 128 + t] = 0.f;  // zero the gemm's accumulator slice
  {
    const int o = t >> 2, k0 = (t & 3) * 16;
    const float* src = &Ww[o * 64 + k0];
    u16 tmp[16];
#pragma unroll
    for (int e = 0; e < 16; ++e) tmp[e] = f2bf(src[e]);
    const int swz = (o & 7) * 8;
#pragma unroll
    for (int v = 0; v < 2; ++v)
      *reinterpret_cast<u16x8*>(&lW[o * 64 + ((k0 + v * 8) ^ swz)]) = *reinterpret_cast<u16x8*>(&tmp[v * 8]);
  }
  {
    const int r = t >> 1, k0 = (t & 1) * 32;
    const float* src = &inp[(row0 + r) * 64 + k0];
    u16 tmp[32];
#pragma unroll
    for (int e = 0; e < 32; ++e) tmp[e] = f2bf(src[e]);
    const int swz = (r & 7) * 8;
#pragma unroll
    for (int v = 0; v < 4; ++v)
      *reinterpret_cast<u16x8*>(&lA[r * 64 + ((k0 + v * 8) ^ swz)]) = *reinterpret_cast<u16x8*>(&tmp[v * 8]);
  }
  __syncthreads();
  f32x4 acc[2][4] = {};
#pragma unroll
  for (int ks = 0; ks < 2; ++ks) {
    const int kk = ks * 32 + (lane >> 4) * 8;
    short8 af[2], bf[4];
#pragma unroll
    for (int m = 0; m < 2; ++m) {
      const int row = w * 32 + m * 16 + (lane & 15);
      af[m] = *reinterpret_cast<const short8*>(&lA[row * 64 + (kk ^ ((row & 7) * 8))]);
    }
#pragma unroll
    for (int n = 0; n < 4; ++n) {
      const int o = n * 16 + (lane & 15);
      bf[n] = *reinterpret_cast<const short8*>(&lW[o * 64 + (kk ^ ((o & 7) * 8))]);
    }
#pragma unroll
    for (int m = 0; m < 2; ++m)
#pragma unroll
      for (int n = 0; n < 4; ++n)
        acc[m][n] = __builtin_amdgcn_mfma_f32_16x16x32_bf16(af[m], bf[n], acc[m][n], 0, 0, 0);
  }
  const int f0 = lane & 15;
  const int rsub = (lane >> 4) * 4;
  float wb[4];
#pragma unroll
  for (int n = 0; n < 4; ++n) wb[n] = Wb[n * 16 + f0];
  const int nloc_base = (hb & 31) * 128;
  float ps[4] = {0.f, 0.f, 0.f, 0.f};
#pragma unroll
  for (int m = 0; m < 2; ++m) {
    const int rl = w * 32 + m * 16 + rsub;
    float vz[4][4];
#pragma unroll
    for (int n = 0; n < 4; ++n) {
      u16 hb4[4];
#pragma unroll
      for (int r = 0; r < 4; ++r) {
        float v = acc[m][n][r] + wb[n];
        if (nloc_base + rl + r == 0) v = 0.f;
        vz[n][r] = v;
        hb4[r] = f2bf(v);
        ps[n] += v;
      }
      *reinterpret_cast<u16x4*>(&h2t[(size_t)(b * 64 + n * 16 + f0) * NN + nloc_base + rl]) =
          *reinterpret_cast<u16x4*>(&hb4[0]);
    }
#pragma unroll
    for (int r = 0; r < 4; ++r) {
      const int ig = nloc_base + rl + r;
      float pv = 0.f;
#pragma unroll
      for (int n = 0; n < 4; ++n) pv += vz[n][r] * a[(size_t)(n * 16 + f0) * NN + ig];
      pv += __shfl_xor(pv, 1);
      pv += __shfl_xor(pv, 2);
      pv += __shfl_xor(pv, 4);
      pv += __shfl_xor(pv, 8);
      if (f0 == 0) p1[(size_t)b * NN + ig] = pv;
    }
  }
#pragma unroll
  for (int n = 0; n < 4; ++n) {
    float v = ps[n];
    v += __shfl_xor(v, 16);
    v += __shfl_xor(v, 32);
    if (lane < 16) wsum[w][n * 16 + f0] = v;
  }
  __syncthreads();
  if (t < 64) hpart[hb * 64 + t] = wsum[0][t] + wsum[1][t] + wsum[2][t] + wsum[3][t];
}

// ---------------- K2: fused GEMM, bit-A via 256-entry byte LUT + counted-vmcnt dbuf ----------------
// s[b,i] += sum_f a2[f,i] * sum_j mask(i,j)*h2t[b*64+f,j]
// A-fragment = ONE ds_read_b128 from lut256[byte] (was 2 conflicted ds_read_b64 + index math).
__global__ __launch_bounds__(256, 4) void k_gemm(const unsigned* __restrict__ Ab, const u16* __restrict__ Bm,
                                                 const float* __restrict__ a, float* __restrict__ s) {
  __shared__ __align__(16) u16 lB0[128 * 64], lB1[128 * 64];
  __shared__ __align__(16) unsigned lAb0[256], lAb1[256];
  __shared__ __align__(16) u16 lut256[256][8];  // byte -> short8 of bf16 0/1 (4 KB)
  const int sid = blockIdx.x;                       // 0..511
  const int wgid = (sid & 7) * 64 + (sid >> 3);     // bijective XCD-chunk swizzle
  const int c0 = (wgid & 3) * 128;
  const int i0 = ((wgid >> 2) & 31) * 128;
  const int z = wgid >> 7;                          // 0..3
  const int t = threadIdx.x, lane = t & 63, w = t >> 6;
  const int wr = w >> 1, wc = w & 1;
  {  // each thread builds its LUT entry
    u16 e[8];
#pragma unroll
    for (int p = 0; p < 8; ++p) e[p] = ((t >> p) & 1) ? 0x3F80 : 0;
    *reinterpret_cast<u16x8*>(&lut256[t][0]) = *reinterpret_cast<u16x8*>(&e[0]);
  }

  const int srow = lane >> 3;
  const int sk = ((lane & 7) ^ srow) * 8;           // pre-swizzled source k-offset (B only)
  const size_t kbase = (size_t)z * 1024;
  const u16* gB = Bm + (size_t)(c0 + w * 32 + srow) * NN + kbase + sk;
  // A-bits source: lane l -> word-row z*32 + it*2 + (l>>5), i = i0 + (l&31)*4 (16 B each)
  const unsigned* gAb = Ab + (size_t)(z * 32 + (lane >> 5)) * NN + i0 + (lane & 31) * 4;

#define STAGE_K(dstB, dstA, it_)                                                             \
  do {                                                                                       \
    __builtin_amdgcn_global_load_lds((gas_t)(gAb + (size_t)(it_) * 2 * NN),                  \
                                     (las_t)((char*)(dstA) + lane * 16), 16, 0, 0);          \
    _Pragma("unroll") for (int c = 0; c < 4; ++c) {                                          \
      __builtin_amdgcn_global_load_lds((gas_t)(gB + (size_t)(8 * c) * NN + (it_) * 64),      \
                                       (las_t)((char*)(dstB) + (w * 32 + 8 * c) * 128 + lane * 16), \
                                       16, 0, 0);                                            \
    }                                                                                        \
  } while (0)

  f32x4 acc[4][4] = {};
  asm volatile("" ::: "memory");
  STAGE_K(lB0, lAb0, 0);   // 5 loads/lane in flight
#pragma unroll 1
  for (int it = 0; it < 16; ++it) {
    if (it < 15) {
      if (it & 1) STAGE_K(lB0, lAb0, it + 1); else STAGE_K(lB1, lAb1, it + 1);  // +5 (tile t+1)
      asm volatile("s_waitcnt vmcnt(5)" ::: "memory");     // drain tile t only
    } else {
      asm volatile("s_waitcnt vmcnt(0)" ::: "memory");
    }
    __builtin_amdgcn_s_barrier();                          // all waves: tile t resident
    asm volatile("" ::: "memory");
    const u16* cB = (it & 1) ? lB1 : lB0;
    const unsigned* cAb = (it & 1) ? lAb1 : lAb0;
    const int q = lane >> 4;
#pragma unroll
    for (int ks = 0; ks < 2; ++ks) {
      short8 af[4], bfr[4];
#pragma unroll
      for (int m = 0; m < 4; ++m) {
        const unsigned wrd = cAb[ks * 128 + wr * 64 + m * 16 + (lane & 15)];
        const unsigned b8 = (wrd >> (q * 8)) & 0xFFu;
        af[m] = *reinterpret_cast<const short8*>(&lut256[b8][0]);
      }
#pragma unroll
      for (int n = 0; n < 4; ++n) {
        const int row = wc * 64 + n * 16 + (lane & 15);
        const int kb = ks * 4 + q;
        bfr[n] = *reinterpret_cast<const short8*>(&cB[row * 64 + ((kb ^ (row & 7)) * 8)]);
      }
#pragma unroll
      for (int m = 0; m < 4; ++m)
#pragma unroll
        for (int n = 0; n < 4; ++n)
          acc[m][n] = __builtin_amdgcn_mfma_f32_16x16x32_bf16(af[m], bfr[n], acc[m][n], 0, 0, 0);
    }
    asm volatile("" ::: "memory");
    __builtin_amdgcn_s_barrier();                          // buffer-reuse protection
  }
#undef STAGE_K
  // fused epilogue: contract cols (f) with a2[f][i], reduce over f-lanes, atomicAdd into s
  const int b = (c0 >> 7) * 2 + wc;
  const int f0 = lane & 15, rsub = (lane >> 4) * 4;
  float pp[4][4];
#pragma unroll
  for (int m = 0; m < 4; ++m) {
    const int irow = i0 + wr * 64 + m * 16 + rsub;
#pragma unroll
    for (int r = 0; r < 4; ++r) pp[m][r] = 0.f;
#pragma unroll
    for (int n = 0; n < 4; ++n) {
      f32x4 a2v = *reinterpret_cast<const f32x4*>(&a[(size_t)(64 + n * 16 + f0) * NN + irow]);
#pragma unroll
      for (int r = 0; r < 4; ++r) pp[m][r] += acc[m][n][r] * a2v[r];
    }
  }
#pragma unroll
  for (int m = 0; m < 4; ++m)
#pragma unroll
    for (int r = 0; r < 4; ++r) {
      float v = pp[m][r];
      v += __shfl_xor(v, 1);
      v += __shfl_xor(v, 2);
      v += __shfl_xor(v, 4);
      v += __shfl_xor(v, 8);
      pp[m][r] = v;
    }
  if (f0 == 0) {
    const int irow = i0 + wr * 64 + rsub;
#pragma unroll
    for (int m = 0; m < 4; ++m)
#pragma unroll
      for (int r = 0; r < 4; ++r)
        atomicAdd(&s[(size_t)b * NN + irow + m * 16 + r], pp[m][r]);
  }
}

// ---------------- K3: out = lrelu((p1 + s) * hsum), hsum reduced from hpart ----------------
__global__ __launch_bounds__(256) void k_final(const float* __restrict__ p1, const float* __restrict__ sg,
                                               const float* __restrict__ hpart, float* __restrict__ out) {
  __shared__ float hp[4][64];
  __shared__ float hs[64], sv[64];
  const int b = blockIdx.x >> 6;
  const int i0 = (blockIdx.x & 63) * 64;
  const int t = threadIdx.x;
  {
    const int f = t & 63, g = t >> 6;
    float acc = 0.f;
#pragma unroll
    for (int sl = 0; sl < 8; ++sl) acc += hpart[(size_t)(b * 32 + g * 8 + sl) * 64 + f];
    hp[g][f] = acc;
  }
  __syncthreads();
  if (t < 64) {
    hs[t] = hp[0][t] + hp[1][t] + hp[2][t] + hp[3][t];
    const int i = i0 + t;
    sv[t] = (i == 0) ? 0.f : (p1[(size_t)b * NN + i] + sg[(size_t)b * NN + i]);
  }
  __syncthreads();
  const int fq = (t & 15) * 4, ir = t >> 4;
#pragma unroll
  for (int pass = 0; pass < 4; ++pass) {
    const int ii = pass * 16 + ir;
    const float svi = sv[ii];
    f32x4 o;
#pragma unroll
    for (int k = 0; k < 4; ++k) {
      float val = svi * hs[fq + k];
      o[k] = (val >= 0.f) ? val : 0.01f * val;
    }
    *reinterpret_cast<f32x4*>(&out[((size_t)b * NN + i0 + ii) * 64 + fq]) = o;
  }
}

extern "C" void kernel_launch(void* const* d_in, const int* in_sizes, int n_in,
                              void* d_out, int out_size, void* d_ws, size_t ws_size,
                              hipStream_t stream) {
  const float* inp = (const float*)d_in[0];
  const int* adj = (const int*)d_in[1];
  const float* Ww = (const float*)d_in[2];
  const float* Wb = (const float*)d_in[3];
  const float* a = (const float*)d_in[4];
  float* out = (float*)d_out;
  char* ws = (char*)d_ws;

  float* s = (float*)ws;                          // 128 KB [8][4096]
  float* hpart = (float*)(ws + 131072);           //  64 KB [256][64]
  float* p1 = (float*)(ws + 196608);              // 128 KB [8][4096]
  unsigned* AbitsT = (unsigned*)(ws + 524288);    //   2 MB [128 jwords][4096 i]
  u16* h2t = (u16*)(ws + 524288 + 2097152);       //   4 MB [512][4096] bf16

  hipLaunchKernelGGL(k_prep, dim3(1280), dim3(256), 0, stream, adj, inp, Ww, Wb, a,
                     AbitsT, h2t, p1, hpart, s);
  hipLaunchKernelGGL(k_gemm, dim3(512), dim3(256), 0, stream, AbitsT, h2t, a, s);
  hipLaunchKernelGGL(k_final, dim3(512), dim3(256), 0, stream, p1, s, hpart, out);
}